// Round 11
// baseline (291.878 us; speedup 1.0000x reference)
//
#include <hip/hip_runtime.h>
#include <stdint.h>

// Problem constants
#define BB 4
#define TT 2048
#define EE 1024
#define HH 16
#define DD 64
#define MM (BB*TT)        // 8192
#define NQKV (3*EE)       // 3072

typedef __bf16 bf16_t;
typedef bf16_t bf16x8 __attribute__((ext_vector_type(8)));
typedef short  s16x4  __attribute__((ext_vector_type(4)));
typedef float  floatx4 __attribute__((ext_vector_type(4)));

__device__ __forceinline__ unsigned short f2bf(float f) {
    unsigned int u = __float_as_uint(f);
    u = (u + 0x7FFFu + ((u >> 16) & 1u)) >> 16;
    return (unsigned short)u;
}

// compiler-mediated f32->bf16 (RNE); backend pairs into v_cvt_pk_bf16_f32 itself.
__device__ __forceinline__ short bfs(float f) {
    return (short)__builtin_bit_cast(unsigned short, (bf16_t)f);
}

__device__ __forceinline__ void load_lds16(const void* g, void* l) {
    __builtin_amdgcn_global_load_lds(
        (const __attribute__((address_space(1))) unsigned int*)g,
        (__attribute__((address_space(3))) unsigned int*)l, 16, 0, 0);
}

// ---------------------------------------------------------------- convert
__global__ void cvt_f32_bf16(const float* __restrict__ in,
                             unsigned short* __restrict__ out, int n) {
    int i = (blockIdx.x * 256 + threadIdx.x) * 4;
    if (i + 3 < n) {
        float4 v = *reinterpret_cast<const float4*>(in + i);
        ushort4 o;
        o.x = f2bf(v.x); o.y = f2bf(v.y); o.z = f2bf(v.z); o.w = f2bf(v.w);
        *reinterpret_cast<ushort4*>(out + i) = o;
    }
}

// ---------------------------------------------------------------- GEMM v5 (B^T input)
// R0's proven structure + chunk-XOR LDS swizzle (R8: SQ_LDS_BANK_CONFLICT 6.29M -> 0,
// time neutral -> conflicts were hidden by 3-block/CU overlap; kept because free).
// Ledger: R5 full conflict fix via row-scatter = +40us (TA merge loss). R1/R2/R4
// hand-scheduled 1-block/CU 256-tiles = 118-133us. This structure = 89.5us, the
// local optimum for the GEMMs. R10 measured it at 113.7us with IDENTICAL per-byte
// counters and uniformly deflated rates -> contended container, not a code effect
// (this round is the clean re-measurement).
template<int N, int K, int EPI>
__global__ __launch_bounds__(256, 3) void gemm_bt(
    const unsigned short* __restrict__ A,
    const unsigned short* __restrict__ Bw,
    const float* __restrict__ bias,
    const float* __restrict__ sscale,
    unsigned short* __restrict__ Qb,
    unsigned short* __restrict__ Kb,
    unsigned short* __restrict__ Vtb,
    float* __restrict__ Cout)
{
    __shared__ __align__(16) unsigned short As[2][128 * 32];   // [k-half][row][32]
    __shared__ __align__(16) unsigned short Bs[2][128 * 32];
    __shared__ float qsc[16];

    const int tid  = threadIdx.x;
    const int lane = tid & 63;
    const int w    = tid >> 6;
    const int quad = lane >> 4;
    const int l16  = lane & 15;
    const int m0   = blockIdx.y * 128;
    const int n0   = blockIdx.x * 128;
    const int wm   = (w & 1) * 64;
    const int wn   = (w >> 1) * 64;

    if (EPI == 0 && tid < 16) qsc[tid] = (1.0f + 0.01f * tanhf(sscale[tid])) * 0.125f;

    floatx4 acc[4][4] = {};

    // read-side swizzled chunk slot (ushort offset): quad ^ ((l16>>1)&3)
    const int rsl = (quad ^ ((l16 >> 1) & 3)) * 8;

    for (int kk = 0; kk < K; kk += 64) {
        __syncthreads();   // WAR: previous pair's fragment reads done
#pragma unroll
        for (int h = 0; h < 2; ++h) {
#pragma unroll
            for (int c = 0; c < 2; ++c) {
                int idx = c * 256 + tid;
                int chk = (idx & 3) ^ ((idx >> 3) & 3);   // chunk-XOR within 64B group
                const unsigned short* ga = A  + (size_t)(m0 + (idx >> 2)) * K + kk + h * 32 + chk * 8;
                load_lds16(ga, &As[h][(c * 256 + w * 64) * 8]);
                const unsigned short* gb = Bw + (size_t)(n0 + (idx >> 2)) * K + kk + h * 32 + chk * 8;
                load_lds16(gb, &Bs[h][(c * 256 + w * 64) * 8]);
            }
        }
        __syncthreads();   // data ready (compiler emits the vmcnt(0) drain here)

#pragma unroll
        for (int h = 0; h < 2; ++h) {
            bf16x8 af[4], bfr[4];
#pragma unroll
            for (int mt = 0; mt < 4; ++mt)
                af[mt] = *reinterpret_cast<const bf16x8*>(&As[h][(wm + mt * 16 + l16) * 32 + rsl]);
#pragma unroll
            for (int nt = 0; nt < 4; ++nt)
                bfr[nt] = *reinterpret_cast<const bf16x8*>(&Bs[h][(wn + nt * 16 + l16) * 32 + rsl]);
#pragma unroll
            for (int mt = 0; mt < 4; ++mt)
#pragma unroll
                for (int nt = 0; nt < 4; ++nt)
                    acc[mt][nt] = __builtin_amdgcn_mfma_f32_16x16x32_bf16(af[mt], bfr[nt], acc[mt][nt], 0, 0, 0);
        }
    }

    if (EPI == 0) {
#pragma unroll
        for (int mt = 0; mt < 4; ++mt) {
            int rowb = m0 + wm + mt * 16 + quad * 4;
#pragma unroll
            for (int nt = 0; nt < 4; ++nt) {
                int col = n0 + wn + nt * 16 + l16;   // 0..3071
                int which = col >> 10;               // 0=q 1=k 2=v
                int e = col & 1023;
                int h = e >> 6, d = e & 63;
                float bsv = bias[col];
#pragma unroll
                for (int r = 0; r < 4; ++r) {
                    int m = rowb + r;                // b*T + t
                    int b = m >> 11, t = m & 2047;
                    float v = acc[mt][nt][r] + bsv;
                    size_t bh = (size_t)(b * HH + h);
                    if (which == 0) {
                        v *= qsc[h];
                        Qb[(bh * TT + t) * DD + d] = f2bf(v);
                    } else if (which == 1) {
                        Kb[(bh * TT + t) * DD + d] = f2bf(v);
                    } else {
                        Vtb[(bh * DD + d) * TT + t] = f2bf(v);
                    }
                }
            }
        }
    } else {
#pragma unroll
        for (int mt = 0; mt < 4; ++mt) {
            int rowb = m0 + wm + mt * 16 + quad * 4;
#pragma unroll
            for (int nt = 0; nt < 4; ++nt) {
                int col = n0 + wn + nt * 16 + l16;
                float bsv = bias[col];
#pragma unroll
                for (int r = 0; r < 4; ++r)
                    Cout[(size_t)(rowb + r) * N + col] = acc[mt][nt][r] + bsv;
            }
        }
    }
}

// ---------------------------------------------------------------- flash attention v10
// v10 = v9 (128 q-rows/block, K/V frags shared by two q-groups, grid 1024) with the
// R9 spill fixed. R9 diagnosis: launch_bounds(256,4) capped VGPRs at 128 < true
// pressure (~130-160) -> accumulator spill -> FETCH+WRITE 620MB of scratch traffic,
// MfmaUtil 9%, 280us. v10: launch_bounds(256,3) -> 168-VGPR budget, no spill,
// 3 blocks/CU (12 waves/CU). Reuse math: K-frag reads, stage traffic and K/V global
// refetch per unit work are HALF of v8's. Compute identical to v8 (group0 kt in
// [0,2qb], group1 kt in [0,2qb+1]; total 4qb+3 MFMA-tiles = the two 64-row blocks
// this replaces).
#define LP 72   // padded LDS row stride: 144B -> dword stride 36
__global__ __launch_bounds__(256, 3) void flash_attn(
    const unsigned short* __restrict__ Qb,
    const unsigned short* __restrict__ Kb,
    const unsigned short* __restrict__ Vtb,
    unsigned short* __restrict__ Ob)
{
    __shared__ __align__(16) unsigned short Ks[2][64 * LP];   // [buf][key][d]
    __shared__ __align__(16) unsigned short Vs[2][64 * LP];   // [buf][d][key]

    const int tid  = threadIdx.x;
    const int lane = tid & 63;
    const int w    = tid >> 6;
    const int quad = lane >> 4;
    const int l16  = lane & 15;
    const int i    = blockIdx.x;
    const int bh   = i & 63;               // 0..63
    const int qb   = 15 - (i >> 6);        // 0..15, heavy first; 128 q-rows per block
    const int row0 = qb * 128 + w * 16;    // group0 rows; group1 = row0 + 64

    // Q fragments for both groups (B-operand: n=qrow, k=d)
    const unsigned short* qbase = &Qb[((size_t)bh * TT + row0 + l16) * DD + quad * 8];
    const bf16x8 qf0 = *reinterpret_cast<const bf16x8*>(qbase);
    const bf16x8 qf1 = *reinterpret_cast<const bf16x8*>(qbase + 32);
    const bf16x8 qg0 = *reinterpret_cast<const bf16x8*>(qbase + 64 * DD);
    const bf16x8 qg1 = *reinterpret_cast<const bf16x8*>(qbase + 64 * DD + 32);

    const s16x4 vones = { (short)0x3F80, (short)0x3F80, (short)0x3F80, (short)0x3F80 };

    floatx4 o[4] = {}, ob[4] = {};
    floatx4 o1 = {}, o1b = {};   // row sums per group

    const int srow = tid >> 3;            // 0..31
    const int scol = (tid & 7) * 8;       // 0..56
    const size_t kgbase = ((size_t)bh * TT + srow) * DD + scol;
    const size_t vgbase = ((size_t)bh * DD + srow) * TT + scol;

    uint4 kr0 = *reinterpret_cast<const uint4*>(&Kb[kgbase]);
    uint4 kr1 = *reinterpret_cast<const uint4*>(&Kb[kgbase + 32 * DD]);
    uint4 vr0 = *reinterpret_cast<const uint4*>(&Vtb[vgbase]);
    uint4 vr1 = *reinterpret_cast<const uint4*>(&Vtb[vgbase + 32 * TT]);

    const int ktmax = 2 * qb + 1;

    for (int kt = 0; kt <= ktmax; ++kt) {
        const int buf = kt & 1;
        *reinterpret_cast<uint4*>(&Ks[buf][srow * LP + scol]) = kr0;
        *reinterpret_cast<uint4*>(&Ks[buf][(srow + 32) * LP + scol]) = kr1;
        *reinterpret_cast<uint4*>(&Vs[buf][srow * LP + scol]) = vr0;
        *reinterpret_cast<uint4*>(&Vs[buf][(srow + 32) * LP + scol]) = vr1;
        __syncthreads();

        if (kt < ktmax) {
            size_t ko = kgbase + (size_t)(kt + 1) * 64 * DD;
            size_t vo = vgbase + (size_t)(kt + 1) * 64;
            kr0 = *reinterpret_cast<const uint4*>(&Kb[ko]);
            kr1 = *reinterpret_cast<const uint4*>(&Kb[ko + 32 * DD]);
            vr0 = *reinterpret_cast<const uint4*>(&Vtb[vo]);
            vr1 = *reinterpret_cast<const uint4*>(&Vtb[vo + 32 * TT]);
        }

        const int keyb  = kt * 64 + quad * 4;
        const int qr0   = row0 + l16;          // group0 q-row; group1 = qr0 + 64
        const bool g0on = (kt <= 2 * qb);      // group0 fully masked at kt = 2qb+1
        const bool g0di = (kt == 2 * qb);
        const bool g1di = (kt == ktmax);

#pragma unroll
        for (int ntk = 0; ntk < 4; ++ntk) {
            const unsigned short* krow = &Ks[buf][(ntk * 16 + l16) * LP + quad * 8];
            bf16x8 kf0 = *reinterpret_cast<const bf16x8*>(krow);
            bf16x8 kf1 = *reinterpret_cast<const bf16x8*>(krow + 32);

            s16x4 pf, pfb;
            if (g0on) {                        // ---- group 0 scores
                floatx4 st = {0.f, 0.f, 0.f, 0.f};
                st = __builtin_amdgcn_mfma_f32_16x16x32_bf16(kf0, qf0, st, 0, 0, 0);
                st = __builtin_amdgcn_mfma_f32_16x16x32_bf16(kf1, qf1, st, 0, 0, 0);
                float p0 = __expf(st[0]), p1 = __expf(st[1]);
                float p2 = __expf(st[2]), p3 = __expf(st[3]);
                if (g0di) {
                    const int kb = keyb + ntk * 16;
                    p0 = (kb + 0 <= qr0) ? p0 : 0.f;
                    p1 = (kb + 1 <= qr0) ? p1 : 0.f;
                    p2 = (kb + 2 <= qr0) ? p2 : 0.f;
                    p3 = (kb + 3 <= qr0) ? p3 : 0.f;
                }
                pf[0] = bfs(p0); pf[1] = bfs(p1); pf[2] = bfs(p2); pf[3] = bfs(p3);
                o1 = __builtin_amdgcn_mfma_f32_16x16x16bf16_1k(pf, vones, o1, 0, 0, 0);
            }
            {                                  // ---- group 1 scores
                floatx4 st = {0.f, 0.f, 0.f, 0.f};
                st = __builtin_amdgcn_mfma_f32_16x16x32_bf16(kf0, qg0, st, 0, 0, 0);
                st = __builtin_amdgcn_mfma_f32_16x16x32_bf16(kf1, qg1, st, 0, 0, 0);
                float p0 = __expf(st[0]), p1 = __expf(st[1]);
                float p2 = __expf(st[2]), p3 = __expf(st[3]);
                if (g1di) {
                    const int kb = keyb + ntk * 16, qr1 = qr0 + 64;
                    p0 = (kb + 0 <= qr1) ? p0 : 0.f;
                    p1 = (kb + 1 <= qr1) ? p1 : 0.f;
                    p2 = (kb + 2 <= qr1) ? p2 : 0.f;
                    p3 = (kb + 3 <= qr1) ? p3 : 0.f;
                }
                pfb[0] = bfs(p0); pfb[1] = bfs(p1); pfb[2] = bfs(p2); pfb[3] = bfs(p3);
                o1b = __builtin_amdgcn_mfma_f32_16x16x16bf16_1k(pfb, vones, o1b, 0, 0, 0);
            }
            // ---- shared V reads feed both groups' PV
#pragma unroll
            for (int dt = 0; dt < 4; ++dt) {
                s16x4 vf = *reinterpret_cast<const s16x4*>(
                    &Vs[buf][(dt * 16 + l16) * LP + ntk * 16 + quad * 4]);
                if (g0on) o[dt] = __builtin_amdgcn_mfma_f32_16x16x16bf16_1k(pf, vf, o[dt], 0, 0, 0);
                ob[dt] = __builtin_amdgcn_mfma_f32_16x16x16bf16_1k(pfb, vf, ob[dt], 0, 0, 0);
            }
        }
    }

    // epilogue: ctx[b, q, h*64+d] bf16  (C-layout: qrow=quad*4+r, d=l16)
    const int b = bh >> 4, h = bh & 15;
#pragma unroll
    for (int r = 0; r < 4; ++r) {
        int q0 = row0 + quad * 4 + r;
        float rl0 = __builtin_amdgcn_rcpf(o1[r]);
        float rl1 = __builtin_amdgcn_rcpf(o1b[r]);
#pragma unroll
        for (int dt = 0; dt < 4; ++dt) {
            Ob[((size_t)(b * TT + q0)) * EE + h * DD + dt * 16 + l16] =
                f2bf(o[dt][r] * rl0);
            Ob[((size_t)(b * TT + q0 + 64)) * EE + h * DD + dt * 16 + l16] =
                f2bf(ob[dt][r] * rl1);
        }
    }
}

// ---------------------------------------------------------------- launch
extern "C" void kernel_launch(void* const* d_in, const int* in_sizes, int n_in,
                              void* d_out, int out_size, void* d_ws, size_t ws_size,
                              hipStream_t stream) {
    const float* hs    = (const float*)d_in[0];
    const float* Wqkv  = (const float*)d_in[1];
    const float* bqkv  = (const float*)d_in[2];
    const float* Wproj = (const float*)d_in[3];
    const float* bproj = (const float*)d_in[4];
    const float* ss    = (const float*)d_in[5];
    // d_in[6] = splat_bias: softmax-invariant (uniform shift of unmasked logits), unused
    float* out = (float*)d_out;

    char* p = (char*)d_ws;
    unsigned short* hsb    = (unsigned short*)p; p += (size_t)MM * EE * 2;      // 16.8 MB (reused as ctx)
    unsigned short* wqkvb  = (unsigned short*)p; p += (size_t)NQKV * EE * 2;    //  6.3 MB
    unsigned short* wprojb = (unsigned short*)p; p += (size_t)EE * EE * 2;      //  2.1 MB
    unsigned short* Qb     = (unsigned short*)p; p += (size_t)BB*HH*TT*DD * 2;  // 16.8 MB
    unsigned short* Kb     = (unsigned short*)p; p += (size_t)BB*HH*TT*DD * 2;  // 16.8 MB
    unsigned short* Vtb    = (unsigned short*)p; p += (size_t)BB*HH*TT*DD * 2;  // 16.8 MB

    cvt_f32_bf16<<<(MM * EE) / 1024, 256, 0, stream>>>(hs, hsb, MM * EE);
    cvt_f32_bf16<<<(NQKV * EE) / 1024, 256, 0, stream>>>(Wqkv, wqkvb, NQKV * EE);
    cvt_f32_bf16<<<(EE * EE) / 1024, 256, 0, stream>>>(Wproj, wprojb, EE * EE);

    gemm_bt<NQKV, EE, 0><<<dim3(NQKV / 128, MM / 128), 256, 0, stream>>>(
        hsb, wqkvb, bqkv, ss, Qb, Kb, Vtb, nullptr);

    flash_attn<<<dim3(1024), 256, 0, stream>>>(Qb, Kb, Vtb, hsb);

    gemm_bt<EE, EE, 1><<<dim3(EE / 128, MM / 128), 256, 0, stream>>>(
        hsb, wprojb, bproj, nullptr, nullptr, nullptr, nullptr, out);
}

// Round 12
// 269.655 us; speedup vs baseline: 1.0824x; 1.0824x over previous
//
#include <hip/hip_runtime.h>
#include <stdint.h>

// Problem constants
#define BB 4
#define TT 2048
#define EE 1024
#define HH 16
#define DD 64
#define MM (BB*TT)        // 8192
#define NQKV (3*EE)       // 3072

typedef __bf16 bf16_t;
typedef bf16_t bf16x8 __attribute__((ext_vector_type(8)));
typedef short  s16x4  __attribute__((ext_vector_type(4)));
typedef float  floatx4 __attribute__((ext_vector_type(4)));

__device__ __forceinline__ unsigned short f2bf(float f) {
    unsigned int u = __float_as_uint(f);
    u = (u + 0x7FFFu + ((u >> 16) & 1u)) >> 16;
    return (unsigned short)u;
}

// compiler-mediated f32->bf16 (RNE); backend pairs into v_cvt_pk_bf16_f32 itself.
__device__ __forceinline__ short bfs(float f) {
    return (short)__builtin_bit_cast(unsigned short, (bf16_t)f);
}

__device__ __forceinline__ void load_lds16(const void* g, void* l) {
    __builtin_amdgcn_global_load_lds(
        (const __attribute__((address_space(1))) unsigned int*)g,
        (__attribute__((address_space(3))) unsigned int*)l, 16, 0, 0);
}

// ---------------------------------------------------------------- fused convert
// One launch converts all three f32->bf16 buffers (saves 2 launch gaps vs R8).
// Ranges in vec4 units; selection is wave-uniform except at the two seams.
#define NV1 ((MM*EE)/4)          // hs      : 2,097,152 vec4
#define NV2 ((NQKV*EE)/4)        // Wqkv    :   786,432
#define NV3 ((EE*EE)/4)          // Wproj   :   262,144
__global__ void cvt_all(const float* __restrict__ s1, unsigned short* __restrict__ d1,
                        const float* __restrict__ s2, unsigned short* __restrict__ d2,
                        const float* __restrict__ s3, unsigned short* __restrict__ d3) {
    int v = blockIdx.x * 256 + threadIdx.x;          // grid sized exactly
    const float* s; unsigned short* d; int i;
    if (v < NV1)            { s = s1; d = d1; i = v; }
    else if (v < NV1 + NV2) { s = s2; d = d2; i = v - NV1; }
    else                    { s = s3; d = d3; i = v - NV1 - NV2; }
    float4 x = *reinterpret_cast<const float4*>(s + i * 4);
    ushort4 o;
    o.x = f2bf(x.x); o.y = f2bf(x.y); o.z = f2bf(x.z); o.w = f2bf(x.w);
    *reinterpret_cast<ushort4*>(d + i * 4) = o;
}

// ---------------------------------------------------------------- GEMM v5 (B^T input)
// R0's proven structure + chunk-XOR LDS swizzle (R8: SQ_LDS_BANK_CONFLICT 6.29M -> 0,
// time neutral -> conflicts were hidden by 3-block/CU overlap; kept because free).
// Ledger: R5 full conflict fix via row-scatter = +40us (TA merge loss). R1/R2/R4
// hand-scheduled 1-block/CU 256-tiles = 118-133us. R10's 113.7us read was container
// contention (identical per-byte counters, uniformly deflated rates).
// This structure = 89.5us, the local optimum for the GEMMs.
template<int N, int K, int EPI>
__global__ __launch_bounds__(256, 3) void gemm_bt(
    const unsigned short* __restrict__ A,
    const unsigned short* __restrict__ Bw,
    const float* __restrict__ bias,
    const float* __restrict__ sscale,
    unsigned short* __restrict__ Qb,
    unsigned short* __restrict__ Kb,
    unsigned short* __restrict__ Vtb,
    float* __restrict__ Cout)
{
    __shared__ __align__(16) unsigned short As[2][128 * 32];   // [k-half][row][32]
    __shared__ __align__(16) unsigned short Bs[2][128 * 32];
    __shared__ float qsc[16];

    const int tid  = threadIdx.x;
    const int lane = tid & 63;
    const int w    = tid >> 6;
    const int quad = lane >> 4;
    const int l16  = lane & 15;
    const int m0   = blockIdx.y * 128;
    const int n0   = blockIdx.x * 128;
    const int wm   = (w & 1) * 64;
    const int wn   = (w >> 1) * 64;

    if (EPI == 0 && tid < 16) qsc[tid] = (1.0f + 0.01f * tanhf(sscale[tid])) * 0.125f;

    floatx4 acc[4][4] = {};

    // read-side swizzled chunk slot (ushort offset): quad ^ ((l16>>1)&3)
    const int rsl = (quad ^ ((l16 >> 1) & 3)) * 8;

    for (int kk = 0; kk < K; kk += 64) {
        __syncthreads();   // WAR: previous pair's fragment reads done
#pragma unroll
        for (int h = 0; h < 2; ++h) {
#pragma unroll
            for (int c = 0; c < 2; ++c) {
                int idx = c * 256 + tid;
                int chk = (idx & 3) ^ ((idx >> 3) & 3);   // chunk-XOR within 64B group
                const unsigned short* ga = A  + (size_t)(m0 + (idx >> 2)) * K + kk + h * 32 + chk * 8;
                load_lds16(ga, &As[h][(c * 256 + w * 64) * 8]);
                const unsigned short* gb = Bw + (size_t)(n0 + (idx >> 2)) * K + kk + h * 32 + chk * 8;
                load_lds16(gb, &Bs[h][(c * 256 + w * 64) * 8]);
            }
        }
        __syncthreads();   // data ready (compiler emits the vmcnt(0) drain here)

#pragma unroll
        for (int h = 0; h < 2; ++h) {
            bf16x8 af[4], bfr[4];
#pragma unroll
            for (int mt = 0; mt < 4; ++mt)
                af[mt] = *reinterpret_cast<const bf16x8*>(&As[h][(wm + mt * 16 + l16) * 32 + rsl]);
#pragma unroll
            for (int nt = 0; nt < 4; ++nt)
                bfr[nt] = *reinterpret_cast<const bf16x8*>(&Bs[h][(wn + nt * 16 + l16) * 32 + rsl]);
#pragma unroll
            for (int mt = 0; mt < 4; ++mt)
#pragma unroll
                for (int nt = 0; nt < 4; ++nt)
                    acc[mt][nt] = __builtin_amdgcn_mfma_f32_16x16x32_bf16(af[mt], bfr[nt], acc[mt][nt], 0, 0, 0);
        }
    }

    if (EPI == 0) {
#pragma unroll
        for (int mt = 0; mt < 4; ++mt) {
            int rowb = m0 + wm + mt * 16 + quad * 4;
#pragma unroll
            for (int nt = 0; nt < 4; ++nt) {
                int col = n0 + wn + nt * 16 + l16;   // 0..3071
                int which = col >> 10;               // 0=q 1=k 2=v
                int e = col & 1023;
                int h = e >> 6, d = e & 63;
                float bsv = bias[col];
#pragma unroll
                for (int r = 0; r < 4; ++r) {
                    int m = rowb + r;                // b*T + t
                    int b = m >> 11, t = m & 2047;
                    float v = acc[mt][nt][r] + bsv;
                    size_t bh = (size_t)(b * HH + h);
                    if (which == 0) {
                        v *= qsc[h];
                        Qb[(bh * TT + t) * DD + d] = f2bf(v);
                    } else if (which == 1) {
                        Kb[(bh * TT + t) * DD + d] = f2bf(v);
                    } else {
                        Vtb[(bh * DD + d) * TT + t] = f2bf(v);
                    }
                }
            }
        }
    } else {
#pragma unroll
        for (int mt = 0; mt < 4; ++mt) {
            int rowb = m0 + wm + mt * 16 + quad * 4;
#pragma unroll
            for (int nt = 0; nt < 4; ++nt) {
                int col = n0 + wn + nt * 16 + l16;
                float bsv = bias[col];
#pragma unroll
                for (int r = 0; r < 4; ++r)
                    Cout[(size_t)(rowb + r) * N + col] = acc[mt][nt][r] + bsv;
            }
        }
    }
}

// ---------------------------------------------------------------- flash attention v8
// REVERT to the R8-proven 64-row version (pre-committed rule from R9/R10: v10's
// 128-row reuse measured 101.5us, VALUBusy 68% -> attn is VALU-bound, so halving
// LDS traffic bought nothing and cost occupancy (4->3 blocks/CU) + 1.33-round tail.
// v8 by subtraction ~86us in R8's 276.3 total.) Structure: one barrier per k-tile,
// reg prefetch, S^T transpose trick, ones-MFMA row sums, diag-split causal mask,
// compiler-paired bf16 casts.
#define LP 72   // padded LDS row stride: 144B -> dword stride 36
__global__ __launch_bounds__(256, 4) void flash_attn(
    const unsigned short* __restrict__ Qb,
    const unsigned short* __restrict__ Kb,
    const unsigned short* __restrict__ Vtb,
    unsigned short* __restrict__ Ob)
{
    __shared__ __align__(16) unsigned short Ks[2][64 * LP];   // [buf][key][d]
    __shared__ __align__(16) unsigned short Vs[2][64 * LP];   // [buf][d][key]

    const int tid  = threadIdx.x;
    const int lane = tid & 63;
    const int w    = tid >> 6;
    const int quad = lane >> 4;
    const int l16  = lane & 15;
    const int i    = blockIdx.x;
    const int bh   = i & 63;               // 0..63
    const int qt   = 31 - (i >> 6);        // 0..31, heavy first
    const int row0 = qt * 64 + w * 16;     // wave's first q row

    const unsigned short* qbase = &Qb[((size_t)bh * TT + row0 + l16) * DD + quad * 8];
    const bf16x8 qf0 = *reinterpret_cast<const bf16x8*>(qbase);
    const bf16x8 qf1 = *reinterpret_cast<const bf16x8*>(qbase + 32);

    const s16x4 vones = { (short)0x3F80, (short)0x3F80, (short)0x3F80, (short)0x3F80 };

    floatx4 o[4] = {};
    floatx4 o1 = {};   // row sums

    const int srow = tid >> 3;            // 0..31
    const int scol = (tid & 7) * 8;       // 0..56
    const size_t kgbase = ((size_t)bh * TT + srow) * DD + scol;
    const size_t vgbase = ((size_t)bh * DD + srow) * TT + scol;

    uint4 kr0 = *reinterpret_cast<const uint4*>(&Kb[kgbase]);
    uint4 kr1 = *reinterpret_cast<const uint4*>(&Kb[kgbase + 32 * DD]);
    uint4 vr0 = *reinterpret_cast<const uint4*>(&Vtb[vgbase]);
    uint4 vr1 = *reinterpret_cast<const uint4*>(&Vtb[vgbase + 32 * TT]);

    for (int kt = 0; kt <= qt; ++kt) {
        const int buf = kt & 1;
        *reinterpret_cast<uint4*>(&Ks[buf][srow * LP + scol]) = kr0;
        *reinterpret_cast<uint4*>(&Ks[buf][(srow + 32) * LP + scol]) = kr1;
        *reinterpret_cast<uint4*>(&Vs[buf][srow * LP + scol]) = vr0;
        *reinterpret_cast<uint4*>(&Vs[buf][(srow + 32) * LP + scol]) = vr1;
        __syncthreads();

        if (kt < qt) {
            size_t ko = kgbase + (size_t)(kt + 1) * 64 * DD;
            size_t vo = vgbase + (size_t)(kt + 1) * 64;
            kr0 = *reinterpret_cast<const uint4*>(&Kb[ko]);
            kr1 = *reinterpret_cast<const uint4*>(&Kb[ko + 32 * DD]);
            vr0 = *reinterpret_cast<const uint4*>(&Vtb[vo]);
            vr1 = *reinterpret_cast<const uint4*>(&Vtb[vo + 32 * TT]);
        }

        const int keyb = kt * 64 + quad * 4;
        const int qr0  = row0 + l16;
        const bool diag = (kt == qt);

#pragma unroll
        for (int ntk = 0; ntk < 4; ++ntk) {
            const unsigned short* krow = &Ks[buf][(ntk * 16 + l16) * LP + quad * 8];
            bf16x8 kf0 = *reinterpret_cast<const bf16x8*>(krow);
            bf16x8 kf1 = *reinterpret_cast<const bf16x8*>(krow + 32);

            floatx4 st = {0.f, 0.f, 0.f, 0.f};
            st = __builtin_amdgcn_mfma_f32_16x16x32_bf16(kf0, qf0, st, 0, 0, 0);
            st = __builtin_amdgcn_mfma_f32_16x16x32_bf16(kf1, qf1, st, 0, 0, 0);

            float p0 = __expf(st[0]), p1 = __expf(st[1]);
            float p2 = __expf(st[2]), p3 = __expf(st[3]);
            if (diag) {               // wave-uniform: mask only on the diagonal tile
                const int kb = keyb + ntk * 16;
                p0 = (kb + 0 <= qr0) ? p0 : 0.f;
                p1 = (kb + 1 <= qr0) ? p1 : 0.f;
                p2 = (kb + 2 <= qr0) ? p2 : 0.f;
                p3 = (kb + 3 <= qr0) ? p3 : 0.f;
            }
            s16x4 pf;
            pf[0] = bfs(p0); pf[1] = bfs(p1); pf[2] = bfs(p2); pf[3] = bfs(p3);

            o1 = __builtin_amdgcn_mfma_f32_16x16x16bf16_1k(pf, vones, o1, 0, 0, 0);
#pragma unroll
            for (int dt = 0; dt < 4; ++dt) {
                s16x4 vf = *reinterpret_cast<const s16x4*>(
                    &Vs[buf][(dt * 16 + l16) * LP + ntk * 16 + quad * 4]);
                o[dt] = __builtin_amdgcn_mfma_f32_16x16x16bf16_1k(pf, vf, o[dt], 0, 0, 0);
            }
        }
    }

    const int b = bh >> 4, h = bh & 15;
#pragma unroll
    for (int r = 0; r < 4; ++r) {
        int q = row0 + quad * 4 + r;
        float rl = __builtin_amdgcn_rcpf(o1[r]);
#pragma unroll
        for (int dt = 0; dt < 4; ++dt)
            Ob[((size_t)(b * TT + q)) * EE + h * DD + dt * 16 + l16] =
                f2bf(o[dt][r] * rl);
    }
}

// ---------------------------------------------------------------- launch
extern "C" void kernel_launch(void* const* d_in, const int* in_sizes, int n_in,
                              void* d_out, int out_size, void* d_ws, size_t ws_size,
                              hipStream_t stream) {
    const float* hs    = (const float*)d_in[0];
    const float* Wqkv  = (const float*)d_in[1];
    const float* bqkv  = (const float*)d_in[2];
    const float* Wproj = (const float*)d_in[3];
    const float* bproj = (const float*)d_in[4];
    const float* ss    = (const float*)d_in[5];
    // d_in[6] = splat_bias: softmax-invariant (uniform shift of unmasked logits), unused
    float* out = (float*)d_out;

    char* p = (char*)d_ws;
    unsigned short* hsb    = (unsigned short*)p; p += (size_t)MM * EE * 2;      // 16.8 MB (reused as ctx)
    unsigned short* wqkvb  = (unsigned short*)p; p += (size_t)NQKV * EE * 2;    //  6.3 MB
    unsigned short* wprojb = (unsigned short*)p; p += (size_t)EE * EE * 2;      //  2.1 MB
    unsigned short* Qb     = (unsigned short*)p; p += (size_t)BB*HH*TT*DD * 2;  // 16.8 MB
    unsigned short* Kb     = (unsigned short*)p; p += (size_t)BB*HH*TT*DD * 2;  // 16.8 MB
    unsigned short* Vtb    = (unsigned short*)p; p += (size_t)BB*HH*TT*DD * 2;  // 16.8 MB

    cvt_all<<<(NV1 + NV2 + NV3) / 256, 256, 0, stream>>>(
        hs, hsb, Wqkv, wqkvb, Wproj, wprojb);

    gemm_bt<NQKV, EE, 0><<<dim3(NQKV / 128, MM / 128), 256, 0, stream>>>(
        hsb, wqkvb, bqkv, ss, Qb, Kb, Vtb, nullptr);

    flash_attn<<<dim3(2048), 256, 0, stream>>>(Qb, Kb, Vtb, hsb);

    gemm_bt<EE, EE, 1><<<dim3(EE / 128, MM / 128), 256, 0, stream>>>(
        hsb, wprojb, bproj, nullptr, nullptr, nullptr, nullptr, out);
}

// Round 13
// 269.215 us; speedup vs baseline: 1.0842x; 1.0016x over previous
//
#include <hip/hip_runtime.h>
#include <stdint.h>

// Problem constants
#define BB 4
#define TT 2048
#define EE 1024
#define HH 16
#define DD 64
#define MM (BB*TT)        // 8192
#define NQKV (3*EE)       // 3072

typedef __bf16 bf16_t;
typedef bf16_t bf16x8 __attribute__((ext_vector_type(8)));
typedef short  s16x4  __attribute__((ext_vector_type(4)));
typedef float  floatx4 __attribute__((ext_vector_type(4)));

__device__ __forceinline__ unsigned short f2bf(float f) {
    unsigned int u = __float_as_uint(f);
    u = (u + 0x7FFFu + ((u >> 16) & 1u)) >> 16;
    return (unsigned short)u;
}

// compiler-mediated f32->bf16 (RNE); backend pairs into v_cvt_pk_bf16_f32 itself.
__device__ __forceinline__ short bfs(float f) {
    return (short)__builtin_bit_cast(unsigned short, (bf16_t)f);
}

__device__ __forceinline__ void load_lds16(const void* g, void* l) {
    __builtin_amdgcn_global_load_lds(
        (const __attribute__((address_space(1))) unsigned int*)g,
        (__attribute__((address_space(3))) unsigned int*)l, 16, 0, 0);
}

// ---------------------------------------------------------------- fused convert
#define NV1 ((MM*EE)/4)          // hs      : 2,097,152 vec4
#define NV2 ((NQKV*EE)/4)        // Wqkv    :   786,432
#define NV3 ((EE*EE)/4)          // Wproj   :   262,144
__global__ void cvt_all(const float* __restrict__ s1, unsigned short* __restrict__ d1,
                        const float* __restrict__ s2, unsigned short* __restrict__ d2,
                        const float* __restrict__ s3, unsigned short* __restrict__ d3) {
    int v = blockIdx.x * 256 + threadIdx.x;          // grid sized exactly
    const float* s; unsigned short* d; int i;
    if (v < NV1)            { s = s1; d = d1; i = v; }
    else if (v < NV1 + NV2) { s = s2; d = d2; i = v - NV1; }
    else                    { s = s3; d = d3; i = v - NV1 - NV2; }
    float4 x = *reinterpret_cast<const float4*>(s + i * 4);
    ushort4 o;
    o.x = f2bf(x.x); o.y = f2bf(x.y); o.z = f2bf(x.z); o.w = f2bf(x.w);
    *reinterpret_cast<ushort4*>(d + i * 4) = o;
}

// ---------------------------------------------------------------- GEMM v6: pipelined + chunk-XOR
// The R4 2-barrier pipelined structure with the R8 chunk-XOR addressing. Ledger:
//  - R0 gemm_bt (3 blk/CU, 2 sync/K-step): 89.5us, the prior best. MfmaUtil 23%.
//  - R4 pipelined (this schedule, FRAGMENT-ORDERED LDS): 118us -- its scattered
//    per-lane global sources broke 64B TA merge groups (the same defect R5
//    isolated at +40us on the 128 structure). Conflicts were already 0.
//  - R8 chunk-XOR on gemm_bt: conflicts 6.29M -> 0 AND no TA inflation (89.5us
//    held). Chunk-XOR = the only pattern satisfying both constraints.
//  - THIS: R4 schedule + chunk-XOR = the fair trial of deep pipelining.
// Geometry: BM=256, BN=128, BK=64 (two 32-halves), 512 thr = 8 waves (4Mx2N),
// wave tile 64x64 (acc[4][4]). LDS ring = 3 tiles (6 K-half slots) = 144KB,
// 1 blk/CU. Schedule: 2 MFMA blocks + 2 barriers per tile; h1 frag reads drain
// under MFMA_h0, next-tile h0 reads drain under MFMA_h1; counted VW(9) waits
// (never 0 until tail); stage-issues placed right after the barrier that makes
// their target slot WAR-safe. Coverage/WAR re-audited group-by-group (R12 notes).
// LDS layout per slot: row-major [rows][32] with chunk-XOR: slot j of row r holds
// chunk j^s(r), s(r)=(r>>1)&3. Staging src chunk = (tid&3)^((tid>>3)&3) keeps each
// 4-lane 64B group intact (TA merge preserved); frag read slot = quad^((l16>>1)&3)
// retrieves chunk quad (proof: same involution both sides; row-stride 512 ushorts
// per 16 rows keeps the +t*512 fragment stride).
#define VW(N) asm volatile("s_waitcnt vmcnt(" #N ")" ::: "memory")
#define BARX() do { __builtin_amdgcn_s_barrier(); asm volatile("" ::: "memory"); } while (0)
#define FRv(p, t) (*reinterpret_cast<const bf16x8*>((p) + (t) * 512))
#define SLOT(kt) (((kt) % 3) * 2)
#define MFMA1(mi, ni, av, bv) \
    acc[mi][ni] = __builtin_amdgcn_mfma_f32_16x16x32_bf16(av, bv, acc[mi][ni], 0, 0, 0)
#define MFMA_SET(s) do { \
    MFMA1(0,0,afr[s][0],bfr[s][0]); MFMA1(0,1,afr[s][0],bfr[s][1]); MFMA1(0,2,afr[s][0],bfr[s][2]); MFMA1(0,3,afr[s][0],bfr[s][3]); \
    MFMA1(1,0,afr[s][1],bfr[s][0]); MFMA1(1,1,afr[s][1],bfr[s][1]); MFMA1(1,2,afr[s][1],bfr[s][2]); MFMA1(1,3,afr[s][1],bfr[s][3]); \
    MFMA1(2,0,afr[s][2],bfr[s][0]); MFMA1(2,1,afr[s][2],bfr[s][1]); MFMA1(2,2,afr[s][2],bfr[s][2]); MFMA1(2,3,afr[s][2],bfr[s][3]); \
    MFMA1(3,0,afr[s][3],bfr[s][0]); MFMA1(3,1,afr[s][3],bfr[s][1]); MFMA1(3,2,afr[s][3],bfr[s][2]); MFMA1(3,3,afr[s][3],bfr[s][3]); \
} while (0)
// stage one K-half: A 256x32 (2 gloads/thr) + B 128x32 (1 gload/thr) = one 3-load
// group. Dest linear (tid*16B within slot); src pre-rotated chunk within its 64B
// row group. Second A load: rows +128 ((idx>>3)&3 invariant under +512).
#define STAGE_H(kt_, h_) do { \
    const unsigned short* _ga = Ag + (kt_) * 64 + (h_) * 32; \
    unsigned short* _la = (unsigned short*)&As[SLOT(kt_) + (h_)][w * 512]; \
    load_lds16(_ga, _la); \
    load_lds16(_ga + (size_t)128 * 1024, _la + 4096); \
    load_lds16(Bg + (kt_) * 64 + (h_) * 32, &Bs[SLOT(kt_) + (h_)][w * 512]); \
} while (0)
#define RDFRAG(st, kt_, h_) do { \
    const unsigned short* _pa = &As[SLOT(kt_) + (h_)][aoff]; \
    afr[st][0] = FRv(_pa, 0); afr[st][1] = FRv(_pa, 1); \
    afr[st][2] = FRv(_pa, 2); afr[st][3] = FRv(_pa, 3); \
    const unsigned short* _pb = &Bs[SLOT(kt_) + (h_)][boff]; \
    bfr[st][0] = FRv(_pb, 0); bfr[st][1] = FRv(_pb, 1); \
    bfr[st][2] = FRv(_pb, 2); bfr[st][3] = FRv(_pb, 3); \
} while (0)
#define TILE(kt_, VA, VB, DS1, DS0, DRD) do { \
    VW(VA); BARX();                       /* bar_A: h1(kt) covered; h1-slot(kt+2) free */ \
    if (DS1) STAGE_H((kt_) + 2, 1); \
    RDFRAG(1, kt_, 1);                    /* h1 frags drain under MFMA_H0 */ \
    __builtin_amdgcn_s_setprio(1); MFMA_SET(0); __builtin_amdgcn_s_setprio(0); \
    VW(VB); BARX();                       /* bar_B: h0(kt+1) covered; h0-slot(kt+3) free */ \
    if (DS0) STAGE_H((kt_) + 3, 0); \
    if (DRD) RDFRAG(0, (kt_) + 1, 0);     /* next h0 frags drain under MFMA_H1 */ \
    __builtin_amdgcn_s_setprio(1); MFMA_SET(1); __builtin_amdgcn_s_setprio(0); \
} while (0)

// EPI 0: qkv epilogue (scatter q/k/v, fold splat-scale * 1/sqrt(D) into q, bf16).
// EPI 1: fp32 + bias to Cout. K = 1024 for both GEMMs.
template<int N, int EPI>
__global__ __launch_bounds__(512, 2) void gemm256(
    const unsigned short* __restrict__ A,
    const unsigned short* __restrict__ Bw,
    const float* __restrict__ bias,
    const float* __restrict__ sscale,
    unsigned short* __restrict__ Qb,
    unsigned short* __restrict__ Kb,
    unsigned short* __restrict__ Vtb,
    float* __restrict__ Cout)
{
    __shared__ __align__(16) unsigned short As[6][8192];   // 3-tile ring x 2 halves, 96KB
    __shared__ __align__(16) unsigned short Bs[6][4096];   // 48KB  (total 144KB, 1 blk/CU)

    const int tid  = threadIdx.x;
    const int lane = tid & 63;
    const int w    = tid >> 6;
    const int quad = lane >> 4;
    const int l16  = lane & 15;

    // XCD swizzle (768%8==0, 256%8==0 -> bijective simple form)
    const int nwg = (int)gridDim.x;
    const int wg  = ((int)blockIdx.x & 7) * (nwg >> 3) + ((int)blockIdx.x >> 3);
    const int nbx = N / 128;
    const int m0  = (wg / nbx) * 256;
    const int n0  = (wg % nbx) * 128;

    const int wm = (w >> 1) * 64;     // wave row offset: 0/64/128/192
    const int wn = (w & 1) * 64;      // wave col offset: 0/64

    // staging per-lane global base: row = tid>>2 (+128 for 2nd A load),
    // chunk = (tid&3)^((tid>>3)&3) -- chunk-XOR within each 64B row group.
    const int chk = (tid & 3) ^ ((tid >> 3) & 3);
    const unsigned short* Ag = A  + (size_t)(m0 + (tid >> 2)) * 1024 + chk * 8;
    const unsigned short* Bg = Bw + (size_t)(n0 + (tid >> 2)) * 1024 + chk * 8;

    // fragment read offsets (ushorts): row-major + read-side XOR slot
    const int rsl  = (quad ^ ((l16 >> 1) & 3)) * 8;
    const int aoff = (wm + l16) * 32 + rsl;
    const int boff = (wn + l16) * 32 + rsl;

    bf16x8 afr[2][4], bfr[2][4];
    floatx4 acc[4][4] = {};

    // prologue: tiles 0,1 full + tile2 h0 (5 groups = 15 loads); VW(9) leaves
    // g3,g4,g5 outstanding -> h0(0),h1(0) complete.
    STAGE_H(0, 0); STAGE_H(0, 1); STAGE_H(1, 0); STAGE_H(1, 1); STAGE_H(2, 0);
    VW(9); BARX();
    RDFRAG(0, 0, 0);

#pragma unroll
    for (int kt = 0; kt < 13; ++kt)
        TILE(kt, 9, 9, 1, 1, 1);
    TILE(13, 9, 9, 1, 0, 1);      // h0(16) doesn't exist
    TILE(14, 6, 3, 0, 0, 1);      // tails: h1(14) has 2 newer groups, h0(15) has 1
    // kt = 15: drain
    VW(0); BARX();
    RDFRAG(1, 15, 1);
    __builtin_amdgcn_s_setprio(1); MFMA_SET(0); MFMA_SET(1); __builtin_amdgcn_s_setprio(0);

    // epilogue: C layout col = l16, row = quad*4 + r (verified mapping)
    if (EPI == 0) {
        const int colb  = n0 + wn;
        const int which = colb >> 10;   // uniform per 128-col block (q|k|v)
#pragma unroll
        for (int nt = 0; nt < 4; ++nt) {
            const int col = colb + nt * 16 + l16;
            const int e = col & 1023;
            const int hh = e >> 6, d = e & 63;
            const float bsv = bias[col];
            float qs = 0.f;
            if (which == 0) qs = (1.0f + 0.01f * tanhf(sscale[hh])) * 0.125f;
#pragma unroll
            for (int mt = 0; mt < 4; ++mt) {
                const int rowb = m0 + wm + mt * 16 + quad * 4;
#pragma unroll
                for (int r = 0; r < 4; ++r) {
                    const int m = rowb + r;           // b*T + t
                    const int b = m >> 11, t = m & 2047;
                    const size_t bh = (size_t)(b * HH + hh);
                    float v = acc[mt][nt][r] + bsv;
                    if (which == 0) {
                        Qb[(bh * TT + t) * DD + d] = f2bf(v * qs);
                    } else if (which == 1) {
                        Kb[(bh * TT + t) * DD + d] = f2bf(v);
                    } else {
                        Vtb[(bh * DD + d) * TT + t] = f2bf(v);
                    }
                }
            }
        }
    } else {
#pragma unroll
        for (int mt = 0; mt < 4; ++mt) {
            const int rowb = m0 + wm + mt * 16 + quad * 4;
#pragma unroll
            for (int nt = 0; nt < 4; ++nt) {
                const int col = n0 + wn + nt * 16 + l16;
                const float bsv = bias[col];
#pragma unroll
                for (int r = 0; r < 4; ++r)
                    Cout[(size_t)(rowb + r) * N + col] = acc[mt][nt][r] + bsv;
            }
        }
    }
}

// ---------------------------------------------------------------- flash attention v8
// (unchanged from R12 -- proven) One barrier per k-tile, reg prefetch, S^T transpose
// trick, ones-MFMA row sums, diag-split causal mask, compiler-paired bf16 casts.
// Ledger: v10 128-row reuse = 101.5us (VALU-bound at 68% -> LDS cut bought nothing,
// occupancy loss hurt). v8 ~86us.
#define LP 72   // padded LDS row stride: 144B -> dword stride 36
__global__ __launch_bounds__(256, 4) void flash_attn(
    const unsigned short* __restrict__ Qb,
    const unsigned short* __restrict__ Kb,
    const unsigned short* __restrict__ Vtb,
    unsigned short* __restrict__ Ob)
{
    __shared__ __align__(16) unsigned short Ks[2][64 * LP];   // [buf][key][d]
    __shared__ __align__(16) unsigned short Vs[2][64 * LP];   // [buf][d][key]

    const int tid  = threadIdx.x;
    const int lane = tid & 63;
    const int w    = tid >> 6;
    const int quad = lane >> 4;
    const int l16  = lane & 15;
    const int i    = blockIdx.x;
    const int bh   = i & 63;               // 0..63
    const int qt   = 31 - (i >> 6);        // 0..31, heavy first
    const int row0 = qt * 64 + w * 16;     // wave's first q row

    const unsigned short* qbase = &Qb[((size_t)bh * TT + row0 + l16) * DD + quad * 8];
    const bf16x8 qf0 = *reinterpret_cast<const bf16x8*>(qbase);
    const bf16x8 qf1 = *reinterpret_cast<const bf16x8*>(qbase + 32);

    const s16x4 vones = { (short)0x3F80, (short)0x3F80, (short)0x3F80, (short)0x3F80 };

    floatx4 o[4] = {};
    floatx4 o1 = {};   // row sums

    const int srow = tid >> 3;            // 0..31
    const int scol = (tid & 7) * 8;       // 0..56
    const size_t kgbase = ((size_t)bh * TT + srow) * DD + scol;
    const size_t vgbase = ((size_t)bh * DD + srow) * TT + scol;

    uint4 kr0 = *reinterpret_cast<const uint4*>(&Kb[kgbase]);
    uint4 kr1 = *reinterpret_cast<const uint4*>(&Kb[kgbase + 32 * DD]);
    uint4 vr0 = *reinterpret_cast<const uint4*>(&Vtb[vgbase]);
    uint4 vr1 = *reinterpret_cast<const uint4*>(&Vtb[vgbase + 32 * TT]);

    for (int kt = 0; kt <= qt; ++kt) {
        const int buf = kt & 1;
        *reinterpret_cast<uint4*>(&Ks[buf][srow * LP + scol]) = kr0;
        *reinterpret_cast<uint4*>(&Ks[buf][(srow + 32) * LP + scol]) = kr1;
        *reinterpret_cast<uint4*>(&Vs[buf][srow * LP + scol]) = vr0;
        *reinterpret_cast<uint4*>(&Vs[buf][(srow + 32) * LP + scol]) = vr1;
        __syncthreads();

        if (kt < qt) {
            size_t ko = kgbase + (size_t)(kt + 1) * 64 * DD;
            size_t vo = vgbase + (size_t)(kt + 1) * 64;
            kr0 = *reinterpret_cast<const uint4*>(&Kb[ko]);
            kr1 = *reinterpret_cast<const uint4*>(&Kb[ko + 32 * DD]);
            vr0 = *reinterpret_cast<const uint4*>(&Vtb[vo]);
            vr1 = *reinterpret_cast<const uint4*>(&Vtb[vo + 32 * TT]);
        }

        const int keyb = kt * 64 + quad * 4;
        const int qr0  = row0 + l16;
        const bool diag = (kt == qt);

#pragma unroll
        for (int ntk = 0; ntk < 4; ++ntk) {
            const unsigned short* krow = &Ks[buf][(ntk * 16 + l16) * LP + quad * 8];
            bf16x8 kf0 = *reinterpret_cast<const bf16x8*>(krow);
            bf16x8 kf1 = *reinterpret_cast<const bf16x8*>(krow + 32);

            floatx4 st = {0.f, 0.f, 0.f, 0.f};
            st = __builtin_amdgcn_mfma_f32_16x16x32_bf16(kf0, qf0, st, 0, 0, 0);
            st = __builtin_amdgcn_mfma_f32_16x16x32_bf16(kf1, qf1, st, 0, 0, 0);

            float p0 = __expf(st[0]), p1 = __expf(st[1]);
            float p2 = __expf(st[2]), p3 = __expf(st[3]);
            if (diag) {               // wave-uniform: mask only on the diagonal tile
                const int kb = keyb + ntk * 16;
                p0 = (kb + 0 <= qr0) ? p0 : 0.f;
                p1 = (kb + 1 <= qr0) ? p1 : 0.f;
                p2 = (kb + 2 <= qr0) ? p2 : 0.f;
                p3 = (kb + 3 <= qr0) ? p3 : 0.f;
            }
            s16x4 pf;
            pf[0] = bfs(p0); pf[1] = bfs(p1); pf[2] = bfs(p2); pf[3] = bfs(p3);

            o1 = __builtin_amdgcn_mfma_f32_16x16x16bf16_1k(pf, vones, o1, 0, 0, 0);
#pragma unroll
            for (int dt = 0; dt < 4; ++dt) {
                s16x4 vf = *reinterpret_cast<const s16x4*>(
                    &Vs[buf][(dt * 16 + l16) * LP + ntk * 16 + quad * 4]);
                o[dt] = __builtin_amdgcn_mfma_f32_16x16x16bf16_1k(pf, vf, o[dt], 0, 0, 0);
            }
        }
    }

    const int b = bh >> 4, h = bh & 15;
#pragma unroll
    for (int r = 0; r < 4; ++r) {
        int q = row0 + quad * 4 + r;
        float rl = __builtin_amdgcn_rcpf(o1[r]);
#pragma unroll
        for (int dt = 0; dt < 4; ++dt)
            Ob[((size_t)(b * TT + q)) * EE + h * DD + dt * 16 + l16] =
                f2bf(o[dt][r] * rl);
    }
}

// ---------------------------------------------------------------- launch
extern "C" void kernel_launch(void* const* d_in, const int* in_sizes, int n_in,
                              void* d_out, int out_size, void* d_ws, size_t ws_size,
                              hipStream_t stream) {
    const float* hs    = (const float*)d_in[0];
    const float* Wqkv  = (const float*)d_in[1];
    const float* bqkv  = (const float*)d_in[2];
    const float* Wproj = (const float*)d_in[3];
    const float* bproj = (const float*)d_in[4];
    const float* ss    = (const float*)d_in[5];
    // d_in[6] = splat_bias: softmax-invariant (uniform shift of unmasked logits), unused
    float* out = (float*)d_out;

    char* p = (char*)d_ws;
    unsigned short* hsb    = (unsigned short*)p; p += (size_t)MM * EE * 2;      // 16.8 MB (reused as ctx)
    unsigned short* wqkvb  = (unsigned short*)p; p += (size_t)NQKV * EE * 2;    //  6.3 MB
    unsigned short* wprojb = (unsigned short*)p; p += (size_t)EE * EE * 2;      //  2.1 MB
    unsigned short* Qb     = (unsigned short*)p; p += (size_t)BB*HH*TT*DD * 2;  // 16.8 MB
    unsigned short* Kb     = (unsigned short*)p; p += (size_t)BB*HH*TT*DD * 2;  // 16.8 MB
    unsigned short* Vtb    = (unsigned short*)p; p += (size_t)BB*HH*TT*DD * 2;  // 16.8 MB

    cvt_all<<<(NV1 + NV2 + NV3) / 256, 256, 0, stream>>>(
        hs, hsb, Wqkv, wqkvb, Wproj, wprojb);

    gemm256<NQKV, 0><<<dim3((MM / 256) * (NQKV / 128)), 512, 0, stream>>>(
        hsb, wqkvb, bqkv, ss, Qb, Kb, Vtb, nullptr);

    flash_attn<<<dim3(2048), 256, 0, stream>>>(Qb, Kb, Vtb, hsb);

    gemm256<EE, 1><<<dim3((MM / 256) * (EE / 128)), 512, 0, stream>>>(
        hsb, wprojb, bproj, nullptr, nullptr, nullptr, nullptr, out);
}